// Round 3
// baseline (208.509 us; speedup 1.0000x reference)
//
#include <hip/hip_runtime.h>
#include <hip/hip_bf16.h>

typedef __bf16 bf16;
typedef __attribute__((ext_vector_type(4))) float f32x4;
typedef __attribute__((ext_vector_type(8))) __bf16 bf16x8;
typedef __attribute__((ext_vector_type(4))) __bf16 bf16x4;

// ---------------------------------------------------------------------------
// GEMM A (projections): act f32 CHANNEL-major [B][256][P], W f32 [O][C],
// out bf16 PIXEL-major [B][P][256].  f32->bf16 conversion fused into staging,
// transpose fused via register 4x4 mini-transpose + XOR-swizzled A tile.
// 128x128 tile, BK=64, 4 waves (2x2 of 64x64), mfma_f32_16x16x32_bf16.
// ---------------------------------------------------------------------------
__global__ __launch_bounds__(256, 2)
void gemm_cm(const float* __restrict__ act, const float* __restrict__ W,
             const float* __restrict__ bias, bf16* __restrict__ out, int P) {
  __shared__ alignas(16) bf16 At[128][64];  // [pixel][k], col XOR-swizzled by ((p>>2)&7)<<3
  __shared__ alignas(16) bf16 Bt[128][64];  // [o][k], linear
  const int t = threadIdx.x;
  const int b = blockIdx.z;
  const int m0 = blockIdx.x * 128;  // pixel base
  const int n0 = blockIdx.y * 128;  // out-channel base
  const int w = t >> 6, l = t & 63;
  const int wr = w >> 1, wc = w & 1;
  const int lrow = l & 15, koff = (l >> 4) * 8;

  const float* actb = act + (size_t)b * 256 * (size_t)P;

  f32x4 acc[4][4];
#pragma unroll
  for (int i = 0; i < 4; ++i)
#pragma unroll
    for (int j = 0; j < 4; ++j) acc[i][j] = (f32x4){0.f, 0.f, 0.f, 0.f};

  for (int kt = 0; kt < 4; ++kt) {
    const int k0 = kt * 64;
    if (kt) __syncthreads();
    // --- A: 4x4 register mini-transpose, swizzled bf16x4 stores ---
#pragma unroll
    for (int u = 0; u < 2; ++u) {
      int unit = u * 256 + t;
      int up = unit & 31;   // pixel quad index (p = up*4..up*4+3)
      int uk = unit >> 5;   // k quad index    (k = uk*4..uk*4+3)
      int ps = m0 + up * 4;
      if (ps > P - 4) ps = P - 4;  // tail tile (P=1600): junk rows, masked in epilogue
      f32x4 r0 = *(const f32x4*)(actb + (size_t)(k0 + uk * 4 + 0) * P + ps);
      f32x4 r1 = *(const f32x4*)(actb + (size_t)(k0 + uk * 4 + 1) * P + ps);
      f32x4 r2 = *(const f32x4*)(actb + (size_t)(k0 + uk * 4 + 2) * P + ps);
      f32x4 r3 = *(const f32x4*)(actb + (size_t)(k0 + uk * 4 + 3) * P + ps);
      int cs = (uk * 4) ^ ((up & 7) << 3);
#pragma unroll
      for (int j = 0; j < 4; ++j) {
        bf16x4 v = {(bf16)r0[j], (bf16)r1[j], (bf16)r2[j], (bf16)r3[j]};
        *(bf16x4*)&At[up * 4 + j][cs] = v;
      }
    }
    // --- B: W rows, f32->bf16, linear ---
#pragma unroll
    for (int it = 0; it < 8; ++it) {
      int idx = it * 256 + t;
      int row = idx >> 4, ce = (idx & 15) * 4;
      f32x4 v = *(const f32x4*)(W + (size_t)(n0 + row) * 256 + k0 + ce);
      bf16x4 h = {(bf16)v[0], (bf16)v[1], (bf16)v[2], (bf16)v[3]};
      *(bf16x4*)&Bt[row][ce] = h;
    }
    __syncthreads();

#pragma unroll
    for (int kk = 0; kk < 2; ++kk) {
      bf16x8 af[4], bv[4];
#pragma unroll
      for (int i = 0; i < 4; ++i) {
        int ar = wr * 64 + i * 16 + lrow;
        int kb = kk * 32 + koff;
        af[i] = *(const bf16x8*)&At[ar][kb ^ (((ar >> 2) & 7) << 3)];
        bv[i] = *(const bf16x8*)&Bt[wc * 64 + i * 16 + lrow][kb];
      }
#pragma unroll
      for (int mi = 0; mi < 4; ++mi)
#pragma unroll
        for (int ni = 0; ni < 4; ++ni)
          acc[mi][ni] = __builtin_amdgcn_mfma_f32_16x16x32_bf16(af[mi], bv[ni], acc[mi][ni], 0, 0, 0);
    }
  }

  bf16* ob = out + (size_t)b * (size_t)P * 256;
#pragma unroll
  for (int mi = 0; mi < 4; ++mi) {
#pragma unroll
    for (int r = 0; r < 4; ++r) {
      int p_ = m0 + wr * 64 + mi * 16 + (l >> 4) * 4 + r;
      if (p_ < P) {
#pragma unroll
        for (int ni = 0; ni < 4; ++ni) {
          int o_ = n0 + wc * 64 + ni * 16 + (l & 15);
          ob[(size_t)p_ * 256 + o_] = (bf16)(acc[mi][ni][r] + bias[o_]);
        }
      }
    }
  }
}

// ---------------------------------------------------------------------------
// GEMM B (final conv): act bf16 PIXEL-major [B][P][256], W f32 [O][C],
// out f32 CHANNEL-major [B][256][P] (= d_out).
// ---------------------------------------------------------------------------
__global__ __launch_bounds__(256, 2)
void gemm_pm(const bf16* __restrict__ act, const float* __restrict__ W,
             const float* __restrict__ bias, float* __restrict__ out, int P) {
  __shared__ alignas(16) bf16 At[128][64];  // [o][k] from W
  __shared__ alignas(16) bf16 Bt[128][64];  // [pixel][k] from act
  const int t = threadIdx.x;
  const int b = blockIdx.z;
  const int m0 = blockIdx.x * 128;  // out-channel base
  const int n0 = blockIdx.y * 128;  // pixel base
  const int w = t >> 6, l = t & 63;
  const int wr = w >> 1, wc = w & 1;
  const int lrow = l & 15, koff = (l >> 4) * 8;

  const bf16* actb = act + (size_t)b * (size_t)P * 256;

  f32x4 acc[4][4];
#pragma unroll
  for (int i = 0; i < 4; ++i)
#pragma unroll
    for (int j = 0; j < 4; ++j) acc[i][j] = (f32x4){0.f, 0.f, 0.f, 0.f};

  for (int kt = 0; kt < 4; ++kt) {
    const int k0 = kt * 64;
    if (kt) __syncthreads();
#pragma unroll
    for (int it = 0; it < 8; ++it) {
      int idx = it * 256 + t;
      int row = idx >> 4, ce = (idx & 15) * 4;
      f32x4 v = *(const f32x4*)(W + (size_t)(m0 + row) * 256 + k0 + ce);
      bf16x4 h = {(bf16)v[0], (bf16)v[1], (bf16)v[2], (bf16)v[3]};
      *(bf16x4*)&At[row][ce] = h;
    }
#pragma unroll
    for (int it = 0; it < 4; ++it) {
      int idx = it * 256 + t;
      int row = idx >> 3, ce = (idx & 7) * 8;
      bf16x8 v = *(const bf16x8*)(actb + (size_t)(n0 + row) * 256 + k0 + ce);
      *(bf16x8*)&Bt[row][ce] = v;
    }
    __syncthreads();

#pragma unroll
    for (int kk = 0; kk < 2; ++kk) {
      bf16x8 af[4], bv[4];
#pragma unroll
      for (int i = 0; i < 4; ++i) {
        af[i] = *(const bf16x8*)&At[wr * 64 + i * 16 + lrow][kk * 32 + koff];
        bv[i] = *(const bf16x8*)&Bt[wc * 64 + i * 16 + lrow][kk * 32 + koff];
      }
#pragma unroll
      for (int mi = 0; mi < 4; ++mi)
#pragma unroll
        for (int ni = 0; ni < 4; ++ni)
          acc[mi][ni] = __builtin_amdgcn_mfma_f32_16x16x32_bf16(af[mi], bv[ni], acc[mi][ni], 0, 0, 0);
    }
  }

  float* ob = out + (size_t)b * 256 * (size_t)P;
#pragma unroll
  for (int mi = 0; mi < 4; ++mi) {
#pragma unroll
    for (int r = 0; r < 4; ++r) {
      int o_ = m0 + wr * 64 + mi * 16 + (l >> 4) * 4 + r;
      float bvf = bias[o_];
#pragma unroll
      for (int ni = 0; ni < 4; ++ni) {
        int p_ = n0 + wc * 64 + ni * 16 + (l & 15);
        ob[(size_t)o_ * P + p_] = acc[mi][ni][r] + bvf;
      }
    }
  }
}

// ---------------------------------------------------------------------------
// score[b][hd][p] = (1/16) * sum_{c<64} Q[p][hd*64+c] * bilinear(K)[p][hd*64+c]
// Q: [B][6400][256] bf16 pixel-major, K: [B][1600][256] bf16 pixel-major.
// ---------------------------------------------------------------------------
__global__ void score_kernel(const bf16* __restrict__ Qpm, const bf16* __restrict__ Kpm,
                             float* __restrict__ score) {
  const int t = threadIdx.x;
  const int p = blockIdx.x * 256 + t;
  const int hd = blockIdx.y, b = blockIdx.z;
  const int x = p / 80, y = p % 80;

  float cx = 0.5f * x - 0.25f;
  int ix = (int)floorf(cx);
  float wx1 = cx - ix;
  int x0 = ix < 0 ? 0 : ix, x1 = (ix + 1 > 39) ? 39 : ix + 1;
  float cy = 0.5f * y - 0.25f;
  int iy = (int)floorf(cy);
  float wy1 = cy - iy;
  int y0 = iy < 0 ? 0 : iy, y1 = (iy + 1 > 39) ? 39 : iy + 1;
  float w00 = (1.f - wx1) * (1.f - wy1), w01 = (1.f - wx1) * wy1;
  float w10 = wx1 * (1.f - wy1), w11 = wx1 * wy1;

  const bf16* q   = Qpm + ((size_t)b * 6400 + p) * 256 + hd * 64;
  const bf16* k00 = Kpm + ((size_t)b * 1600 + x0 * 40 + y0) * 256 + hd * 64;
  const bf16* k01 = Kpm + ((size_t)b * 1600 + x0 * 40 + y1) * 256 + hd * 64;
  const bf16* k10 = Kpm + ((size_t)b * 1600 + x1 * 40 + y0) * 256 + hd * 64;
  const bf16* k11 = Kpm + ((size_t)b * 1600 + x1 * 40 + y1) * 256 + hd * 64;

  float dot = 0.f;
#pragma unroll
  for (int i = 0; i < 8; ++i) {
    bf16x8 qv = *(const bf16x8*)(q + i * 8);
    bf16x8 a = *(const bf16x8*)(k00 + i * 8);
    bf16x8 c = *(const bf16x8*)(k01 + i * 8);
    bf16x8 d = *(const bf16x8*)(k10 + i * 8);
    bf16x8 e = *(const bf16x8*)(k11 + i * 8);
#pragma unroll
    for (int j = 0; j < 8; ++j) {
      float kup = w00 * (float)a[j] + w01 * (float)c[j] + w10 * (float)d[j] + w11 * (float)e[j];
      dot += (float)qv[j] * kup;
    }
  }
  score[((size_t)b * 4 + hd) * 6400 + p] = dot * 0.0625f;
}

// ---------------------------------------------------------------------------
// In-place column softmax over x (per b,hd,y), x4 (R2 sum) folded in.
// ---------------------------------------------------------------------------
__global__ void smax_kernel(float* __restrict__ score) {
  __shared__ float s[6400];
  const int hd = blockIdx.x, b = blockIdx.y, t = threadIdx.x;
  float* buf = score + ((size_t)b * 4 + hd) * 6400;
  for (int i = t; i < 6400; i += 256) s[i] = buf[i];
  __syncthreads();
  if (t < 80) {
    const int y = t;
    float m = -1e30f;
    for (int x = 0; x < 80; ++x) m = fmaxf(m, s[x * 80 + y]);
    float sum = 0.f;
    for (int x = 0; x < 80; ++x) {
      float e = __expf(s[x * 80 + y] - m);
      s[x * 80 + y] = e;
      sum += e;
    }
    float inv = 4.0f / sum;
    for (int x = 0; x < 80; ++x) buf[x * 80 + y] = s[x * 80 + y] * inv;
  }
}

// ---------------------------------------------------------------------------
// outpm[b][p][c] = attn[b][hd(c)][p] * bilinear(V)[c][p]   (bf16 pixel-major)
// ---------------------------------------------------------------------------
__global__ void outgen_kernel(const bf16* __restrict__ Vpm, const float* __restrict__ attn,
                              bf16* __restrict__ outpm) {
  __shared__ float Vx[40][256];
  __shared__ float at[4][80];
  const int x = blockIdx.x, b = blockIdx.y, t = threadIdx.x;

  float cx = 0.5f * x - 0.25f;
  int ix = (int)floorf(cx);
  float wx1 = cx - ix, wx0 = 1.f - wx1;
  int tx0 = ix < 0 ? 0 : ix, tx1 = (ix + 1 > 39) ? 39 : ix + 1;

  const bf16* r0 = Vpm + ((size_t)b * 1600 + tx0 * 40) * 256;
  const bf16* r1 = Vpm + ((size_t)b * 1600 + tx1 * 40) * 256;
  for (int ty = 0; ty < 40; ++ty)
    Vx[ty][t] = wx0 * (float)r0[ty * 256 + t] + wx1 * (float)r1[ty * 256 + t];
  for (int i = t; i < 320; i += 256) {
    int hd = i / 80, y = i % 80;
    at[hd][y] = attn[((size_t)b * 4 + hd) * 6400 + x * 80 + y];
  }
  __syncthreads();

  const int hd = t >> 6;
  bf16* ob = outpm + ((size_t)b * 6400 + x * 80) * 256;
  for (int y = 0; y < 80; ++y) {
    float cyv = 0.5f * y - 0.25f;
    int iy = (int)floorf(cyv);
    float wy1 = cyv - iy;
    int ty0 = iy < 0 ? 0 : iy, ty1 = (iy + 1 > 39) ? 39 : iy + 1;
    float v = (1.f - wy1) * Vx[ty0][t] + wy1 * Vx[ty1][t];
    ob[(size_t)y * 256 + t] = (bf16)(at[hd][y] * v);
  }
}

// ---------------------------------------------------------------------------
extern "C" void kernel_launch(void* const* d_in, const int* in_sizes, int n_in,
                              void* d_out, int out_size, void* d_ws, size_t ws_size,
                              hipStream_t stream) {
  const float* query = (const float*)d_in[0];
  const float* key   = (const float*)d_in[1];
  const float* wq    = (const float*)d_in[2];
  const float* bq    = (const float*)d_in[3];
  const float* wk    = (const float*)d_in[4];
  const float* bk    = (const float*)d_in[5];
  const float* wv    = (const float*)d_in[6];
  const float* bv    = (const float*)d_in[7];
  const float* wo    = (const float*)d_in[8];
  const float* bo    = (const float*)d_in[9];

  // ws layout (85.2 MB): outpm | Kpm | Vpm | score(+attn in-place)
  char* ws = (char*)d_ws;
  bf16*  outpm = (bf16*)(ws);              // 52,428,800 B
  bf16*  Kpm   = (bf16*)(ws + 52428800);   // 13,107,200 B
  bf16*  Vpm   = (bf16*)(ws + 65536000);   // 13,107,200 B
  float* score = (float*)(ws + 78643200);  //  6,553,600 B
  bf16*  Qpm   = (bf16*)d_out;             // scratch in d_out (dead before final GEMM)

  gemm_cm<<<dim3(50, 2, 16), 256, 0, stream>>>(query, wq, bq, Qpm, 6400);
  gemm_cm<<<dim3(13, 2, 16), 256, 0, stream>>>(key, wk, bk, Kpm, 1600);
  gemm_cm<<<dim3(13, 2, 16), 256, 0, stream>>>(key, wv, bv, Vpm, 1600);
  score_kernel<<<dim3(25, 4, 16), 256, 0, stream>>>(Qpm, Kpm, score);
  smax_kernel<<<dim3(4, 16), 256, 0, stream>>>(score);
  outgen_kernel<<<dim3(80, 16), 256, 0, stream>>>(Vpm, score, outpm);
  gemm_pm<<<dim3(2, 50, 16), 256, 0, stream>>>(outpm, wo, bo, (float*)d_out, 6400);
}

// Round 5
// 202.002 us; speedup vs baseline: 1.0322x; 1.0322x over previous
//
#include <hip/hip_runtime.h>
#include <hip/hip_bf16.h>

typedef __bf16 bf16;
typedef __attribute__((ext_vector_type(4))) float f32x4;
typedef __attribute__((ext_vector_type(8))) __bf16 bf16x8;
typedef __attribute__((ext_vector_type(4))) __bf16 bf16x4;

// ===========================================================================
// GEMM A (projections): act f32 CHANNEL-major [B][256][P], W f32 [O][C],
// out bf16 PIXEL-major [B][P][256].
// Pipelined: reg-prefetch kt+1 global loads before compute(kt), LDS dbuf,
// one barrier per K-step. XOR swizzle key ((row&7)<<3) on both tiles.
// Dual-output form: blockIdx.y>>1 selects (W0,b0,out0) vs (W1,b1,out1) so the
// K and V projections fuse into one dispatch (Q passes the same triple twice).
// ===========================================================================
__global__ __launch_bounds__(256, 2)
void gemm_cm(const float* __restrict__ act,
             const float* __restrict__ W0, const float* __restrict__ b0, bf16* __restrict__ out0,
             const float* __restrict__ W1, const float* __restrict__ b1, bf16* __restrict__ out1,
             int P) {
  __shared__ alignas(16) bf16 At[2][128][64];  // [pixel][k] (transposed in staging)
  __shared__ alignas(16) bf16 Bt[2][128][64];  // [o][k]
  const int t = threadIdx.x;
  const int b = blockIdx.z;
  const int m0 = blockIdx.x * 128;
  const int sel = blockIdx.y >> 1;
  const int n0 = (blockIdx.y & 1) * 128;
  const float* W    = sel ? W1 : W0;
  const float* bias = sel ? b1 : b0;
  bf16*        out  = sel ? out1 : out0;

  const int w = t >> 6, l = t & 63;
  const int wr = w >> 1, wc = w & 1;
  const int lrow = l & 15, koff = (l >> 4) * 8;

  const float* actb = act + (size_t)b * 256 * (size_t)P;

  // staging regs (statically indexed everywhere)
  f32x4 Ar[2][4];
  f32x4 Br[8];

  auto LOAD = [&](int kt) {
    const int k0 = kt * 64;
#pragma unroll
    for (int u = 0; u < 2; ++u) {
      int unit = u * 256 + t;
      int up = unit & 31, uk = unit >> 5;
      int ps = m0 + up * 4;
      if (ps > P - 4) ps = P - 4;  // tail tile: duplicated valid rows, masked in epilogue
#pragma unroll
      for (int j = 0; j < 4; ++j)
        Ar[u][j] = *(const f32x4*)(actb + (size_t)(k0 + uk * 4 + j) * P + ps);
    }
#pragma unroll
    for (int it = 0; it < 8; ++it) {
      int idx = it * 256 + t;
      int row = idx >> 4, ce = (idx & 15) * 4;
      Br[it] = *(const f32x4*)(W + (size_t)(n0 + row) * 256 + k0 + ce);
    }
  };

  auto STORE = [&](int buf) {
#pragma unroll
    for (int u = 0; u < 2; ++u) {
      int unit = u * 256 + t;
      int up = unit & 31, uk = unit >> 5;
#pragma unroll
      for (int j = 0; j < 4; ++j) {  // 4x4 register mini-transpose
        int row = up * 4 + j;
        int cs = (uk * 4) ^ ((row & 7) << 3);
        bf16x4 v = {(bf16)Ar[u][0][j], (bf16)Ar[u][1][j], (bf16)Ar[u][2][j], (bf16)Ar[u][3][j]};
        *(bf16x4*)&At[buf][row][cs] = v;
      }
    }
#pragma unroll
    for (int it = 0; it < 8; ++it) {
      int idx = it * 256 + t;
      int row = idx >> 4, ce = (idx & 15) * 4;
      int cs = ce ^ ((row & 7) << 3);
      bf16x4 h = {(bf16)Br[it][0], (bf16)Br[it][1], (bf16)Br[it][2], (bf16)Br[it][3]};
      *(bf16x4*)&Bt[buf][row][cs] = h;
    }
  };

  f32x4 acc[4][4];
#pragma unroll
  for (int i = 0; i < 4; ++i)
#pragma unroll
    for (int j = 0; j < 4; ++j) acc[i][j] = (f32x4){0.f, 0.f, 0.f, 0.f};

  auto COMPUTE = [&](int buf) {
#pragma unroll
    for (int kk = 0; kk < 2; ++kk) {
      bf16x8 af[4], bv[4];
      const int kb = kk * 32 + koff;
#pragma unroll
      for (int i = 0; i < 4; ++i) {
        int ar = wr * 64 + i * 16 + lrow;
        int br = wc * 64 + i * 16 + lrow;
        af[i] = *(const bf16x8*)&At[buf][ar][kb ^ ((ar & 7) << 3)];
        bv[i] = *(const bf16x8*)&Bt[buf][br][kb ^ ((br & 7) << 3)];
      }
#pragma unroll
      for (int mi = 0; mi < 4; ++mi)
#pragma unroll
        for (int ni = 0; ni < 4; ++ni)
          acc[mi][ni] = __builtin_amdgcn_mfma_f32_16x16x32_bf16(af[mi], bv[ni], acc[mi][ni], 0, 0, 0);
    }
  };

  LOAD(0);
  STORE(0);
  __syncthreads();
#pragma unroll
  for (int kt = 0; kt < 4; ++kt) {
    if (kt < 3) LOAD(kt + 1);        // issue early: HBM latency hides under MFMA
    COMPUTE(kt & 1);
    if (kt < 3) STORE((kt + 1) & 1); // vmcnt drain happens here, after compute
    __syncthreads();
  }

  bf16* ob = out + (size_t)b * (size_t)P * 256;
#pragma unroll
  for (int mi = 0; mi < 4; ++mi) {
#pragma unroll
    for (int r = 0; r < 4; ++r) {
      int p_ = m0 + wr * 64 + mi * 16 + (l >> 4) * 4 + r;
      if (p_ < P) {
#pragma unroll
        for (int ni = 0; ni < 4; ++ni) {
          int o_ = n0 + wc * 64 + ni * 16 + (l & 15);
          ob[(size_t)p_ * 256 + o_] = (bf16)(acc[mi][ni][r] + bias[o_]);
        }
      }
    }
  }
}

// ===========================================================================
// GEMM B (final conv): act bf16 PIXEL-major [B][P][256], W f32 [O][C],
// out f32 CHANNEL-major [B][256][P] (= d_out). Same pipeline structure.
// ===========================================================================
__global__ __launch_bounds__(256, 2)
void gemm_pm(const bf16* __restrict__ act, const float* __restrict__ W,
             const float* __restrict__ bias, float* __restrict__ out, int P) {
  __shared__ alignas(16) bf16 At[2][128][64];  // [o][k] from W
  __shared__ alignas(16) bf16 Bt[2][128][64];  // [pixel][k] from act
  const int t = threadIdx.x;
  const int b = blockIdx.z;
  const int m0 = blockIdx.x * 128;  // out-channel base
  const int n0 = blockIdx.y * 128;  // pixel base
  const int w = t >> 6, l = t & 63;
  const int wr = w >> 1, wc = w & 1;
  const int lrow = l & 15, koff = (l >> 4) * 8;

  const bf16* actb = act + (size_t)b * (size_t)P * 256;

  f32x4 Ar[8];
  bf16x8 Brr[4];

  auto LOAD = [&](int kt) {
    const int k0 = kt * 64;
#pragma unroll
    for (int it = 0; it < 8; ++it) {
      int idx = it * 256 + t;
      int row = idx >> 4, ce = (idx & 15) * 4;
      Ar[it] = *(const f32x4*)(W + (size_t)(m0 + row) * 256 + k0 + ce);
    }
#pragma unroll
    for (int it = 0; it < 4; ++it) {
      int idx = it * 256 + t;
      int row = idx >> 3, ce = (idx & 7) * 8;
      Brr[it] = *(const bf16x8*)(actb + (size_t)(n0 + row) * 256 + k0 + ce);
    }
  };

  auto STORE = [&](int buf) {
#pragma unroll
    for (int it = 0; it < 8; ++it) {
      int idx = it * 256 + t;
      int row = idx >> 4, ce = (idx & 15) * 4;
      int cs = ce ^ ((row & 7) << 3);
      bf16x4 h = {(bf16)Ar[it][0], (bf16)Ar[it][1], (bf16)Ar[it][2], (bf16)Ar[it][3]};
      *(bf16x4*)&At[buf][row][cs] = h;
    }
#pragma unroll
    for (int it = 0; it < 4; ++it) {
      int idx = it * 256 + t;
      int row = idx >> 3, ce = (idx & 7) * 8;
      int cs = ce ^ ((row & 7) << 3);
      *(bf16x8*)&Bt[buf][row][cs] = Brr[it];
    }
  };

  f32x4 acc[4][4];
#pragma unroll
  for (int i = 0; i < 4; ++i)
#pragma unroll
    for (int j = 0; j < 4; ++j) acc[i][j] = (f32x4){0.f, 0.f, 0.f, 0.f};

  auto COMPUTE = [&](int buf) {
#pragma unroll
    for (int kk = 0; kk < 2; ++kk) {
      bf16x8 af[4], bv[4];
      const int kb = kk * 32 + koff;
#pragma unroll
      for (int i = 0; i < 4; ++i) {
        int ar = wr * 64 + i * 16 + lrow;
        int br = wc * 64 + i * 16 + lrow;
        af[i] = *(const bf16x8*)&At[buf][ar][kb ^ ((ar & 7) << 3)];
        bv[i] = *(const bf16x8*)&Bt[buf][br][kb ^ ((br & 7) << 3)];
      }
#pragma unroll
      for (int mi = 0; mi < 4; ++mi)
#pragma unroll
        for (int ni = 0; ni < 4; ++ni)
          acc[mi][ni] = __builtin_amdgcn_mfma_f32_16x16x32_bf16(af[mi], bv[ni], acc[mi][ni], 0, 0, 0);
    }
  };

  LOAD(0);
  STORE(0);
  __syncthreads();
#pragma unroll
  for (int kt = 0; kt < 4; ++kt) {
    if (kt < 3) LOAD(kt + 1);
    COMPUTE(kt & 1);
    if (kt < 3) STORE((kt + 1) & 1);
    __syncthreads();
  }

  float* ob = out + (size_t)b * 256 * (size_t)P;
#pragma unroll
  for (int mi = 0; mi < 4; ++mi) {
#pragma unroll
    for (int r = 0; r < 4; ++r) {
      int o_ = m0 + wr * 64 + mi * 16 + (l >> 4) * 4 + r;
      float bvf = bias[o_];
#pragma unroll
      for (int ni = 0; ni < 4; ++ni) {
        int p_ = n0 + wc * 64 + ni * 16 + (l & 15);
        ob[(size_t)o_ * P + p_] = acc[mi][ni][r] + bvf;
      }
    }
  }
}

// ---------------------------------------------------------------------------
// score[b][hd][p] = (1/16) * sum_{c<64} Q[p][hd*64+c] * bilinear(K)[p][hd*64+c]
// ---------------------------------------------------------------------------
__global__ void score_kernel(const bf16* __restrict__ Qpm, const bf16* __restrict__ Kpm,
                             float* __restrict__ score) {
  const int t = threadIdx.x;
  const int p = blockIdx.x * 256 + t;
  const int hd = blockIdx.y, b = blockIdx.z;
  const int x = p / 80, y = p % 80;

  float cx = 0.5f * x - 0.25f;
  int ix = (int)floorf(cx);
  float wx1 = cx - ix;
  int x0 = ix < 0 ? 0 : ix, x1 = (ix + 1 > 39) ? 39 : ix + 1;
  float cy = 0.5f * y - 0.25f;
  int iy = (int)floorf(cy);
  float wy1 = cy - iy;
  int y0 = iy < 0 ? 0 : iy, y1 = (iy + 1 > 39) ? 39 : iy + 1;
  float w00 = (1.f - wx1) * (1.f - wy1), w01 = (1.f - wx1) * wy1;
  float w10 = wx1 * (1.f - wy1), w11 = wx1 * wy1;

  const bf16* q   = Qpm + ((size_t)b * 6400 + p) * 256 + hd * 64;
  const bf16* k00 = Kpm + ((size_t)b * 1600 + x0 * 40 + y0) * 256 + hd * 64;
  const bf16* k01 = Kpm + ((size_t)b * 1600 + x0 * 40 + y1) * 256 + hd * 64;
  const bf16* k10 = Kpm + ((size_t)b * 1600 + x1 * 40 + y0) * 256 + hd * 64;
  const bf16* k11 = Kpm + ((size_t)b * 1600 + x1 * 40 + y1) * 256 + hd * 64;

  float dot = 0.f;
#pragma unroll
  for (int i = 0; i < 8; ++i) {
    bf16x8 qv = *(const bf16x8*)(q + i * 8);
    bf16x8 a = *(const bf16x8*)(k00 + i * 8);
    bf16x8 c = *(const bf16x8*)(k01 + i * 8);
    bf16x8 d = *(const bf16x8*)(k10 + i * 8);
    bf16x8 e = *(const bf16x8*)(k11 + i * 8);
#pragma unroll
    for (int j = 0; j < 8; ++j) {
      float kup = w00 * (float)a[j] + w01 * (float)c[j] + w10 * (float)d[j] + w11 * (float)e[j];
      dot += (float)qv[j] * kup;
    }
  }
  score[((size_t)b * 4 + hd) * 6400 + p] = dot * 0.0625f;
}

// ---------------------------------------------------------------------------
// In-place column softmax over x (per b,hd,y), x4 (R2 sum) folded in.
// ---------------------------------------------------------------------------
__global__ void smax_kernel(float* __restrict__ score) {
  __shared__ float s[6400];
  const int hd = blockIdx.x, b = blockIdx.y, t = threadIdx.x;
  float* buf = score + ((size_t)b * 4 + hd) * 6400;
  for (int i = t; i < 6400; i += 256) s[i] = buf[i];
  __syncthreads();
  if (t < 80) {
    const int y = t;
    float m = -1e30f;
    for (int x = 0; x < 80; ++x) m = fmaxf(m, s[x * 80 + y]);
    float sum = 0.f;
    for (int x = 0; x < 80; ++x) {
      float e = __expf(s[x * 80 + y] - m);
      s[x * 80 + y] = e;
      sum += e;
    }
    float inv = 4.0f / sum;
    for (int x = 0; x < 80; ++x) buf[x * 80 + y] = s[x * 80 + y] * inv;
  }
}

// ---------------------------------------------------------------------------
// outpm[b][p][c] = attn[b][hd(c)][p] * bilinear(V)[c][p]   (bf16 pixel-major)
// ---------------------------------------------------------------------------
__global__ void outgen_kernel(const bf16* __restrict__ Vpm, const float* __restrict__ attn,
                              bf16* __restrict__ outpm) {
  __shared__ float Vx[40][256];
  __shared__ float at[4][80];
  const int x = blockIdx.x, b = blockIdx.y, t = threadIdx.x;

  float cx = 0.5f * x - 0.25f;
  int ix = (int)floorf(cx);
  float wx1 = cx - ix, wx0 = 1.f - wx1;
  int tx0 = ix < 0 ? 0 : ix, tx1 = (ix + 1 > 39) ? 39 : ix + 1;

  const bf16* r0 = Vpm + ((size_t)b * 1600 + tx0 * 40) * 256;
  const bf16* r1 = Vpm + ((size_t)b * 1600 + tx1 * 40) * 256;
  for (int ty = 0; ty < 40; ++ty)
    Vx[ty][t] = wx0 * (float)r0[ty * 256 + t] + wx1 * (float)r1[ty * 256 + t];
  for (int i = t; i < 320; i += 256) {
    int hd = i / 80, y = i % 80;
    at[hd][y] = attn[((size_t)b * 4 + hd) * 6400 + x * 80 + y];
  }
  __syncthreads();

  const int hd = t >> 6;
  bf16* ob = outpm + ((size_t)b * 6400 + x * 80) * 256;
  for (int y = 0; y < 80; ++y) {
    float cyv = 0.5f * y - 0.25f;
    int iy = (int)floorf(cyv);
    float wy1 = cyv - iy;
    int ty0 = iy < 0 ? 0 : iy, ty1 = (iy + 1 > 39) ? 39 : iy + 1;
    float v = (1.f - wy1) * Vx[ty0][t] + wy1 * Vx[ty1][t];
    ob[(size_t)y * 256 + t] = (bf16)(at[hd][y] * v);
  }
}

// ---------------------------------------------------------------------------
extern "C" void kernel_launch(void* const* d_in, const int* in_sizes, int n_in,
                              void* d_out, int out_size, void* d_ws, size_t ws_size,
                              hipStream_t stream) {
  const float* query = (const float*)d_in[0];
  const float* key   = (const float*)d_in[1];
  const float* wq    = (const float*)d_in[2];
  const float* bq    = (const float*)d_in[3];
  const float* wk    = (const float*)d_in[4];
  const float* bk    = (const float*)d_in[5];
  const float* wv    = (const float*)d_in[6];
  const float* bv    = (const float*)d_in[7];
  const float* wo    = (const float*)d_in[8];
  const float* bo    = (const float*)d_in[9];

  // ws layout (85.2 MB): outpm | Kpm | Vpm | score(+attn in-place)
  char* ws = (char*)d_ws;
  bf16*  outpm = (bf16*)(ws);              // 52,428,800 B
  bf16*  Kpm   = (bf16*)(ws + 52428800);   // 13,107,200 B
  bf16*  Vpm   = (bf16*)(ws + 65536000);   // 13,107,200 B
  float* score = (float*)(ws + 78643200);  //  6,553,600 B
  bf16*  Qpm   = (bf16*)d_out;             // scratch in d_out (dead before final GEMM)

  gemm_cm<<<dim3(50, 2, 16), 256, 0, stream>>>(query, wq, bq, Qpm, wq, bq, Qpm, 6400);
  gemm_cm<<<dim3(13, 4, 16), 256, 0, stream>>>(key, wk, bk, Kpm, wv, bv, Vpm, 1600);
  score_kernel<<<dim3(25, 4, 16), 256, 0, stream>>>(Qpm, Kpm, score);
  smax_kernel<<<dim3(4, 16), 256, 0, stream>>>(score);
  outgen_kernel<<<dim3(80, 16), 256, 0, stream>>>(Vpm, score, outpm);
  gemm_pm<<<dim3(2, 50, 16), 256, 0, stream>>>(outpm, wo, bo, (float*)d_out, 6400);
}

// Round 6
// 201.182 us; speedup vs baseline: 1.0364x; 1.0041x over previous
//
#include <hip/hip_runtime.h>
#include <hip/hip_bf16.h>

typedef __bf16 bf16;
typedef __attribute__((ext_vector_type(4))) float f32x4;
typedef __attribute__((ext_vector_type(8))) __bf16 bf16x8;
typedef __attribute__((ext_vector_type(4))) __bf16 bf16x4;

// ===========================================================================
// Projection GEMM: act f32 CHANNEL-major [B][256][P], W f32 [O][C].
// EPI=0: out bf16 CHANNEL-major [B][256][P]  (contiguous bf16x4 stores; Q)
// EPI=1: out bf16 PIXEL-major  [B][P][256]  (scattered 2B stores; K,V)
// Dual-output: blockIdx.y>>1 selects (W0,b0,out0)/(W1,b1,out1) (K+V fused).
// launch_bounds(256,1): allow ~200 VGPR so the LOAD-early prefetch regs
// survive across COMPUTE (at (256,2) the allocator sank the loads -> no
// prefetch; that was rounds 3-5's latency wall).
// ===========================================================================
template <int EPI>
__global__ __launch_bounds__(256, 1)
void gemm_cm(const float* __restrict__ act,
             const float* __restrict__ W0, const float* __restrict__ b0, bf16* __restrict__ out0,
             const float* __restrict__ W1, const float* __restrict__ b1, bf16* __restrict__ out1,
             int P) {
  __shared__ alignas(16) bf16 At[2][128][64];  // [pixel][k] (transposed in staging)
  __shared__ alignas(16) bf16 Bt[2][128][64];  // [o][k]
  const int t = threadIdx.x;
  const int b = blockIdx.z;
  const int m0 = blockIdx.x * 128;
  const int sel = blockIdx.y >> 1;
  const int n0 = (blockIdx.y & 1) * 128;
  const float* W    = sel ? W1 : W0;
  const float* bias = sel ? b1 : b0;
  bf16*        out  = sel ? out1 : out0;

  const int w = t >> 6, l = t & 63;
  const int wr = w >> 1, wc = w & 1;
  const int lrow = l & 15, koff = (l >> 4) * 8;

  const float* actb = act + (size_t)b * 256 * (size_t)P;

  f32x4 Ar[2][4];
  f32x4 Br[8];

  auto LOAD = [&](int kt) {
    const int k0 = kt * 64;
#pragma unroll
    for (int u = 0; u < 2; ++u) {
      int unit = u * 256 + t;
      int up = unit & 31, uk = unit >> 5;
      int ps = m0 + up * 4;
      if (ps > P - 4) ps = P - 4;  // tail tile: dup rows, masked in epilogue
#pragma unroll
      for (int j = 0; j < 4; ++j)
        Ar[u][j] = *(const f32x4*)(actb + (size_t)(k0 + uk * 4 + j) * P + ps);
    }
#pragma unroll
    for (int it = 0; it < 8; ++it) {
      int idx = it * 256 + t;
      int row = idx >> 4, ce = (idx & 15) * 4;
      Br[it] = *(const f32x4*)(W + (size_t)(n0 + row) * 256 + k0 + ce);
    }
  };

  auto STORE = [&](int buf) {
#pragma unroll
    for (int u = 0; u < 2; ++u) {
      int unit = u * 256 + t;
      int up = unit & 31, uk = unit >> 5;
#pragma unroll
      for (int j = 0; j < 4; ++j) {  // 4x4 register mini-transpose
        int row = up * 4 + j;
        int cs = (uk * 4) ^ ((row & 7) << 3);
        bf16x4 v = {(bf16)Ar[u][0][j], (bf16)Ar[u][1][j], (bf16)Ar[u][2][j], (bf16)Ar[u][3][j]};
        *(bf16x4*)&At[buf][row][cs] = v;
      }
    }
#pragma unroll
    for (int it = 0; it < 8; ++it) {
      int idx = it * 256 + t;
      int row = idx >> 4, ce = (idx & 15) * 4;
      int cs = ce ^ ((row & 7) << 3);
      bf16x4 h = {(bf16)Br[it][0], (bf16)Br[it][1], (bf16)Br[it][2], (bf16)Br[it][3]};
      *(bf16x4*)&Bt[buf][row][cs] = h;
    }
  };

  f32x4 acc[4][4];
#pragma unroll
  for (int i = 0; i < 4; ++i)
#pragma unroll
    for (int j = 0; j < 4; ++j) acc[i][j] = (f32x4){0.f, 0.f, 0.f, 0.f};

  auto COMPUTE = [&](int buf) {
#pragma unroll
    for (int kk = 0; kk < 2; ++kk) {
      bf16x8 af[4], bv[4];
      const int kb = kk * 32 + koff;
#pragma unroll
      for (int i = 0; i < 4; ++i) {
        int ar = wr * 64 + i * 16 + lrow;
        int br = wc * 64 + i * 16 + lrow;
        af[i] = *(const bf16x8*)&At[buf][ar][kb ^ ((ar & 7) << 3)];
        bv[i] = *(const bf16x8*)&Bt[buf][br][kb ^ ((br & 7) << 3)];
      }
#pragma unroll
      for (int mi = 0; mi < 4; ++mi)
#pragma unroll
        for (int ni = 0; ni < 4; ++ni)
          acc[mi][ni] = __builtin_amdgcn_mfma_f32_16x16x32_bf16(af[mi], bv[ni], acc[mi][ni], 0, 0, 0);
    }
  };

  LOAD(0);
  STORE(0);
  __syncthreads();
#pragma unroll
  for (int kt = 0; kt < 4; ++kt) {
    if (kt < 3) LOAD(kt + 1);        // prefetch: needs VGPR headroom (launch_bounds 1)
    COMPUTE(kt & 1);
    if (kt < 3) STORE((kt + 1) & 1);
    __syncthreads();
  }

  if (EPI == 0) {
    // channel-major: out[b][o][p], r runs along p -> contiguous bf16x4
    bf16* ob = out + (size_t)b * 256 * (size_t)P;
#pragma unroll
    for (int mi = 0; mi < 4; ++mi) {
      int pbase = m0 + wr * 64 + mi * 16 + (l >> 4) * 4;
#pragma unroll
      for (int ni = 0; ni < 4; ++ni) {
        int o_ = n0 + wc * 64 + ni * 16 + (l & 15);
        float bvf = bias[o_];
        bf16x4 v = {(bf16)(acc[mi][ni][0] + bvf), (bf16)(acc[mi][ni][1] + bvf),
                    (bf16)(acc[mi][ni][2] + bvf), (bf16)(acc[mi][ni][3] + bvf)};
        if (pbase < P) *(bf16x4*)(ob + (size_t)o_ * P + pbase) = v;
      }
    }
  } else {
    // pixel-major: out[b][p][o]
    bf16* ob = out + (size_t)b * (size_t)P * 256;
#pragma unroll
    for (int mi = 0; mi < 4; ++mi) {
#pragma unroll
      for (int r = 0; r < 4; ++r) {
        int p_ = m0 + wr * 64 + mi * 16 + (l >> 4) * 4 + r;
        if (p_ < P) {
#pragma unroll
          for (int ni = 0; ni < 4; ++ni) {
            int o_ = n0 + wc * 64 + ni * 16 + (l & 15);
            ob[(size_t)p_ * 256 + o_] = (bf16)(acc[mi][ni][r] + bias[o_]);
          }
        }
      }
    }
  }
}

// ===========================================================================
// Final conv GEMM: act bf16 PIXEL-major [B][P][256] (A operand, m=pixel),
// W f32 [O][C] (B operand), out f32 CHANNEL-major [B][256][P] (= d_out),
// r runs along p -> contiguous f32x4 stores.
// ===========================================================================
__global__ __launch_bounds__(256, 1)
void gemm_out(const bf16* __restrict__ act, const float* __restrict__ W,
              const float* __restrict__ bias, float* __restrict__ out, int P) {
  __shared__ alignas(16) bf16 At[2][128][64];  // [pixel][k] from act
  __shared__ alignas(16) bf16 Bt[2][128][64];  // [o][k] from W
  const int t = threadIdx.x;
  const int b = blockIdx.z;
  const int m0 = blockIdx.x * 128;  // pixel base
  const int n0 = blockIdx.y * 128;  // out-channel base
  const int w = t >> 6, l = t & 63;
  const int wr = w >> 1, wc = w & 1;
  const int lrow = l & 15, koff = (l >> 4) * 8;

  const bf16* actb = act + (size_t)b * (size_t)P * 256;

  bf16x8 Arr[4];
  f32x4 Br[8];

  auto LOAD = [&](int kt) {
    const int k0 = kt * 64;
#pragma unroll
    for (int it = 0; it < 4; ++it) {
      int idx = it * 256 + t;
      int row = idx >> 3, ce = (idx & 7) * 8;
      Arr[it] = *(const bf16x8*)(actb + (size_t)(m0 + row) * 256 + k0 + ce);
    }
#pragma unroll
    for (int it = 0; it < 8; ++it) {
      int idx = it * 256 + t;
      int row = idx >> 4, ce = (idx & 15) * 4;
      Br[it] = *(const f32x4*)(W + (size_t)(n0 + row) * 256 + k0 + ce);
    }
  };

  auto STORE = [&](int buf) {
#pragma unroll
    for (int it = 0; it < 4; ++it) {
      int idx = it * 256 + t;
      int row = idx >> 3, ce = (idx & 7) * 8;
      int cs = ce ^ ((row & 7) << 3);
      *(bf16x8*)&At[buf][row][cs] = Arr[it];
    }
#pragma unroll
    for (int it = 0; it < 8; ++it) {
      int idx = it * 256 + t;
      int row = idx >> 4, ce = (idx & 15) * 4;
      int cs = ce ^ ((row & 7) << 3);
      bf16x4 h = {(bf16)Br[it][0], (bf16)Br[it][1], (bf16)Br[it][2], (bf16)Br[it][3]};
      *(bf16x4*)&Bt[buf][row][cs] = h;
    }
  };

  f32x4 acc[4][4];
#pragma unroll
  for (int i = 0; i < 4; ++i)
#pragma unroll
    for (int j = 0; j < 4; ++j) acc[i][j] = (f32x4){0.f, 0.f, 0.f, 0.f};

  auto COMPUTE = [&](int buf) {
#pragma unroll
    for (int kk = 0; kk < 2; ++kk) {
      bf16x8 af[4], bv[4];
      const int kb = kk * 32 + koff;
#pragma unroll
      for (int i = 0; i < 4; ++i) {
        int ar = wr * 64 + i * 16 + lrow;
        int br = wc * 64 + i * 16 + lrow;
        af[i] = *(const bf16x8*)&At[buf][ar][kb ^ ((ar & 7) << 3)];
        bv[i] = *(const bf16x8*)&Bt[buf][br][kb ^ ((br & 7) << 3)];
      }
#pragma unroll
      for (int mi = 0; mi < 4; ++mi)
#pragma unroll
        for (int ni = 0; ni < 4; ++ni)
          acc[mi][ni] = __builtin_amdgcn_mfma_f32_16x16x32_bf16(af[mi], bv[ni], acc[mi][ni], 0, 0, 0);
    }
  };

  LOAD(0);
  STORE(0);
  __syncthreads();
#pragma unroll
  for (int kt = 0; kt < 4; ++kt) {
    if (kt < 3) LOAD(kt + 1);
    COMPUTE(kt & 1);
    if (kt < 3) STORE((kt + 1) & 1);
    __syncthreads();
  }

  float* ob = out + (size_t)b * 256 * (size_t)P;
#pragma unroll
  for (int mi = 0; mi < 4; ++mi) {
    int pbase = m0 + wr * 64 + mi * 16 + (l >> 4) * 4;
#pragma unroll
    for (int ni = 0; ni < 4; ++ni) {
      int o_ = n0 + wc * 64 + ni * 16 + (l & 15);
      float bvf = bias[o_];
      f32x4 v = {acc[mi][ni][0] + bvf, acc[mi][ni][1] + bvf,
                 acc[mi][ni][2] + bvf, acc[mi][ni][3] + bvf};
      *(f32x4*)(ob + (size_t)o_ * P + pbase) = v;
    }
  }
}

// ---------------------------------------------------------------------------
// score[b][hd][p] = (1/16) * sum_{c<64} Qcm[hd*64+c][p] * bilinear(K)[p][hd*64+c]
// Qcm: [B][256][6400] bf16 channel-major; Kpm: [B][1600][256] bf16 pixel-major.
// ---------------------------------------------------------------------------
__global__ void score_kernel(const bf16* __restrict__ Qcm, const bf16* __restrict__ Kpm,
                             float* __restrict__ score) {
  const int t = threadIdx.x;
  const int p = blockIdx.x * 256 + t;
  const int hd = blockIdx.y, b = blockIdx.z;
  const int x = p / 80, y = p % 80;

  float cx = 0.5f * x - 0.25f;
  int ix = (int)floorf(cx);
  float wx1 = cx - ix;
  int x0 = ix < 0 ? 0 : ix, x1 = (ix + 1 > 39) ? 39 : ix + 1;
  float cy = 0.5f * y - 0.25f;
  int iy = (int)floorf(cy);
  float wy1 = cy - iy;
  int y0 = iy < 0 ? 0 : iy, y1 = (iy + 1 > 39) ? 39 : iy + 1;
  float w00 = (1.f - wx1) * (1.f - wy1), w01 = (1.f - wx1) * wy1;
  float w10 = wx1 * (1.f - wy1), w11 = wx1 * wy1;

  const bf16* q   = Qcm + ((size_t)b * 256 + hd * 64) * 6400 + p;  // stride 6400 per c
  const bf16* k00 = Kpm + ((size_t)b * 1600 + x0 * 40 + y0) * 256 + hd * 64;
  const bf16* k01 = Kpm + ((size_t)b * 1600 + x0 * 40 + y1) * 256 + hd * 64;
  const bf16* k10 = Kpm + ((size_t)b * 1600 + x1 * 40 + y0) * 256 + hd * 64;
  const bf16* k11 = Kpm + ((size_t)b * 1600 + x1 * 40 + y1) * 256 + hd * 64;

  float dot = 0.f;
#pragma unroll
  for (int i = 0; i < 8; ++i) {
    bf16x8 a = *(const bf16x8*)(k00 + i * 8);
    bf16x8 c = *(const bf16x8*)(k01 + i * 8);
    bf16x8 d = *(const bf16x8*)(k10 + i * 8);
    bf16x8 e = *(const bf16x8*)(k11 + i * 8);
#pragma unroll
    for (int j = 0; j < 8; ++j) {
      float kup = w00 * (float)a[j] + w01 * (float)c[j] + w10 * (float)d[j] + w11 * (float)e[j];
      float qc = (float)q[(size_t)(i * 8 + j) * 6400];
      dot += qc * kup;
    }
  }
  score[((size_t)b * 4 + hd) * 6400 + p] = dot * 0.0625f;
}

// ---------------------------------------------------------------------------
// In-place column softmax over x (per b,hd,y), x4 (R2 sum) folded in.
// ---------------------------------------------------------------------------
__global__ void smax_kernel(float* __restrict__ score) {
  __shared__ float s[6400];
  const int hd = blockIdx.x, b = blockIdx.y, t = threadIdx.x;
  float* buf = score + ((size_t)b * 4 + hd) * 6400;
  for (int i = t; i < 6400; i += 256) s[i] = buf[i];
  __syncthreads();
  if (t < 80) {
    const int y = t;
    float m = -1e30f;
    for (int x = 0; x < 80; ++x) m = fmaxf(m, s[x * 80 + y]);
    float sum = 0.f;
    for (int x = 0; x < 80; ++x) {
      float e = __expf(s[x * 80 + y] - m);
      s[x * 80 + y] = e;
      sum += e;
    }
    float inv = 4.0f / sum;
    for (int x = 0; x < 80; ++x) buf[x * 80 + y] = s[x * 80 + y] * inv;
  }
}

// ---------------------------------------------------------------------------
// outpm[b][p][c] = attn[b][hd(c)][p] * bilinear(V)[c][p]   (bf16 pixel-major)
// ---------------------------------------------------------------------------
__global__ void outgen_kernel(const bf16* __restrict__ Vpm, const float* __restrict__ attn,
                              bf16* __restrict__ outpm) {
  __shared__ float Vx[40][256];
  __shared__ float at[4][80];
  const int x = blockIdx.x, b = blockIdx.y, t = threadIdx.x;

  float cx = 0.5f * x - 0.25f;
  int ix = (int)floorf(cx);
  float wx1 = cx - ix, wx0 = 1.f - wx1;
  int tx0 = ix < 0 ? 0 : ix, tx1 = (ix + 1 > 39) ? 39 : ix + 1;

  const bf16* r0 = Vpm + ((size_t)b * 1600 + tx0 * 40) * 256;
  const bf16* r1 = Vpm + ((size_t)b * 1600 + tx1 * 40) * 256;
  for (int ty = 0; ty < 40; ++ty)
    Vx[ty][t] = wx0 * (float)r0[ty * 256 + t] + wx1 * (float)r1[ty * 256 + t];
  for (int i = t; i < 320; i += 256) {
    int hd = i / 80, y = i % 80;
    at[hd][y] = attn[((size_t)b * 4 + hd) * 6400 + x * 80 + y];
  }
  __syncthreads();

  const int hd = t >> 6;
  bf16* ob = outpm + ((size_t)b * 6400 + x * 80) * 256;
  for (int y = 0; y < 80; ++y) {
    float cyv = 0.5f * y - 0.25f;
    int iy = (int)floorf(cyv);
    float wy1 = cyv - iy;
    int ty0 = iy < 0 ? 0 : iy, ty1 = (iy + 1 > 39) ? 39 : iy + 1;
    float v = (1.f - wy1) * Vx[ty0][t] + wy1 * Vx[ty1][t];
    ob[(size_t)y * 256 + t] = (bf16)(at[hd][y] * v);
  }
}

// ---------------------------------------------------------------------------
extern "C" void kernel_launch(void* const* d_in, const int* in_sizes, int n_in,
                              void* d_out, int out_size, void* d_ws, size_t ws_size,
                              hipStream_t stream) {
  const float* query = (const float*)d_in[0];
  const float* key   = (const float*)d_in[1];
  const float* wq    = (const float*)d_in[2];
  const float* bq    = (const float*)d_in[3];
  const float* wk    = (const float*)d_in[4];
  const float* bk    = (const float*)d_in[5];
  const float* wv    = (const float*)d_in[6];
  const float* bv    = (const float*)d_in[7];
  const float* wo    = (const float*)d_in[8];
  const float* bo    = (const float*)d_in[9];

  // ws layout (85.2 MB): outpm | Kpm | Vpm | score(+attn in-place)
  char* ws = (char*)d_ws;
  bf16*  outpm = (bf16*)(ws);              // 52,428,800 B
  bf16*  Kpm   = (bf16*)(ws + 52428800);   // 13,107,200 B
  bf16*  Vpm   = (bf16*)(ws + 65536000);   // 13,107,200 B
  float* score = (float*)(ws + 78643200);  //  6,553,600 B
  bf16*  Qcm   = (bf16*)d_out;             // scratch in d_out (dead before gemm_out)

  gemm_cm<0><<<dim3(50, 2, 16), 256, 0, stream>>>(query, wq, bq, Qcm, wq, bq, Qcm, 6400);
  gemm_cm<1><<<dim3(13, 4, 16), 256, 0, stream>>>(key, wk, bk, Kpm, wv, bv, Vpm, 1600);
  score_kernel<<<dim3(25, 4, 16), 256, 0, stream>>>(Qcm, Kpm, score);
  smax_kernel<<<dim3(4, 16), 256, 0, stream>>>(score);
  outgen_kernel<<<dim3(80, 16), 256, 0, stream>>>(Vpm, score, outpm);
  gemm_out<<<dim3(50, 2, 16), 256, 0, stream>>>(outpm, wo, bo, (float*)d_out, 6400);
}

// Round 7
// 179.617 us; speedup vs baseline: 1.1609x; 1.1201x over previous
//
#include <hip/hip_runtime.h>
#include <hip/hip_bf16.h>

typedef __bf16 bf16;
typedef __attribute__((ext_vector_type(4))) float f32x4;
typedef __attribute__((ext_vector_type(8))) __bf16 bf16x8;
typedef __attribute__((ext_vector_type(4))) __bf16 bf16x4;

// async global->LDS, 16B per lane; LDS dest must be wave-uniform base + lane*16
static __device__ __forceinline__ void gl16(const void* g, void* l) {
  __builtin_amdgcn_global_load_lds((const __attribute__((address_space(1))) void*)g,
                                   (__attribute__((address_space(3))) void*)l, 16, 0, 0);
}
// fragment read from a [128][64] bf16 tile, 16B-unit XOR swizzle by (row&7)
static __device__ __forceinline__ bf16x8 frag(const bf16* tile, int row, int kb) {
  return *(const bf16x8*)(tile + row * 64 + ((((kb) >> 3) ^ (row & 7)) << 3));
}

// ---------------------------------------------------------------------------
// Weight prepass: 4x [256][256] f32 -> bf16 row-major.
// ---------------------------------------------------------------------------
__global__ void wpre(const float* __restrict__ w0, const float* __restrict__ w1,
                     const float* __restrict__ w2, const float* __restrict__ w3,
                     bf16* __restrict__ dst) {
  const float* srcs[4] = {w0, w1, w2, w3};
  const float* s = srcs[blockIdx.y];
  bf16* d = dst + (size_t)blockIdx.y * 65536;
  int base = blockIdx.x * 2048 + threadIdx.x * 8;
  f32x4 a = *(const f32x4*)(s + base);
  f32x4 b = *(const f32x4*)(s + base + 4);
  bf16x8 v = {(bf16)a[0], (bf16)a[1], (bf16)a[2], (bf16)a[3],
              (bf16)b[0], (bf16)b[1], (bf16)b[2], (bf16)b[3]};
  *(bf16x8*)(d + base) = v;
}

// ---------------------------------------------------------------------------
// Fused Q-projection + score.  query f32 channel-major [B][256][6400].
// Block: 128 pixels x 128 out-channels (= heads n0/64, n0/64+1), 512 threads,
// 8 waves as 2(m) x 4(n), wave-tile 64x32, BK=64, LDS dbuf, B via gload_lds.
// Epilogue: Q-tile -> LDS, then per-(pixel,head) dot with bilinear K -> score.
// ---------------------------------------------------------------------------
__global__ __launch_bounds__(512, 1)
void qgemm_score(const float* __restrict__ query, const bf16* __restrict__ Wq,
                 const float* __restrict__ bq, const bf16* __restrict__ Kpm,
                 float* __restrict__ score) {
  __shared__ alignas(16) char smem[65536];
  const int t = threadIdx.x;
  const int b = blockIdx.z;
  const int m0 = blockIdx.x * 128;
  const int n0 = blockIdx.y * 128;
  const int w = t >> 6, l = t & 63;
  const int wr = w & 1, wc = w >> 1;
  const int lrow = l & 15, koff = (l >> 4) * 8;
  const int up = t & 31, uk = t >> 5;
  const float* actb = query + (size_t)b * 256 * 6400;

  f32x4 Ar[4];
  f32x4 acc[4][2];
#pragma unroll
  for (int i = 0; i < 4; ++i)
#pragma unroll
    for (int j = 0; j < 2; ++j) acc[i][j] = (f32x4){0.f, 0.f, 0.f, 0.f};

  auto Ab = [&](int buf) { return (bf16*)(smem + buf * 16384); };
  auto Bb = [&](int buf) { return (bf16*)(smem + 32768 + buf * 16384); };

  auto GLOADB = [&](int kt, int buf) {
    const int k0 = kt * 64;
#pragma unroll
    for (int call = 0; call < 2; ++call) {
      int idx = call * 512 + t;
      int row = idx >> 3, u = idx & 7;
      gl16(Wq + (size_t)(n0 + row) * 256 + k0 + ((u ^ (row & 7)) << 3), Bb(buf) + idx * 8);
    }
  };
  auto ALOAD = [&](int kt) {
    const int k0 = kt * 64;
    int ps = m0 + up * 4;
#pragma unroll
    for (int j = 0; j < 4; ++j)
      Ar[j] = *(const f32x4*)(actb + (size_t)(k0 + uk * 4 + j) * 6400 + ps);
  };
  auto ASTORE = [&](int buf) {
#pragma unroll
    for (int j = 0; j < 4; ++j) {
      int row = up * 4 + j;
      int cs = (uk * 4) ^ ((row & 7) << 3);
      bf16x4 v = {(bf16)Ar[0][j], (bf16)Ar[1][j], (bf16)Ar[2][j], (bf16)Ar[3][j]};
      *(bf16x4*)(Ab(buf) + row * 64 + cs) = v;
    }
  };
  auto COMPUTE = [&](int buf) {
#pragma unroll
    for (int kk = 0; kk < 2; ++kk) {
      const int kb = kk * 32 + koff;
      bf16x8 af[4], bv[2];
#pragma unroll
      for (int i = 0; i < 4; ++i) af[i] = frag(Ab(buf), wr * 64 + i * 16 + lrow, kb);
#pragma unroll
      for (int j = 0; j < 2; ++j) bv[j] = frag(Bb(buf), wc * 32 + j * 16 + lrow, kb);
#pragma unroll
      for (int i = 0; i < 4; ++i)
#pragma unroll
        for (int j = 0; j < 2; ++j)
          acc[i][j] = __builtin_amdgcn_mfma_f32_16x16x32_bf16(af[i], bv[j], acc[i][j], 0, 0, 0);
    }
  };

  GLOADB(0, 0);
  ALOAD(0);
  ASTORE(0);
  __syncthreads();
#pragma unroll
  for (int kt = 0; kt < 4; ++kt) {
    const int cur = kt & 1;
    if (kt < 3) { GLOADB(kt + 1, cur ^ 1); ALOAD(kt + 1); }
    __builtin_amdgcn_sched_barrier(0);
    COMPUTE(cur);
    if (kt < 3) ASTORE(cur ^ 1);
    __syncthreads();
  }

  // ---- dump Q tile (with bias) to LDS [128 px][136 ch-stride] ----
  bf16* Qs = (bf16*)smem;
#pragma unroll
  for (int mi = 0; mi < 4; ++mi) {
#pragma unroll
    for (int ni = 0; ni < 2; ++ni) {
      int ch = wc * 32 + ni * 16 + (l & 15);
      float bvf = bq[n0 + ch];
#pragma unroll
      for (int r = 0; r < 4; ++r) {
        int p = wr * 64 + mi * 16 + (l >> 4) * 4 + r;
        Qs[p * 136 + ch] = (bf16)(acc[mi][ni][r] + bvf);
      }
    }
  }
  __syncthreads();

  // ---- score: one thread per (pixel, local head) ----
  if (t < 256) {
    int pl = t & 127, hl = t >> 7;
    int hd = (n0 >> 6) + hl;
    int p = m0 + pl;
    int x = p / 80, y = p % 80;
    float cx = 0.5f * x - 0.25f;
    int ix = (int)floorf(cx);
    float wx1 = cx - ix;
    int x0 = ix < 0 ? 0 : ix, x1 = (ix + 1 > 39) ? 39 : ix + 1;
    float cy = 0.5f * y - 0.25f;
    int iy = (int)floorf(cy);
    float wy1 = cy - iy;
    int y0 = iy < 0 ? 0 : iy, y1 = (iy + 1 > 39) ? 39 : iy + 1;
    float w00 = (1.f - wx1) * (1.f - wy1), w01 = (1.f - wx1) * wy1;
    float w10 = wx1 * (1.f - wy1), w11 = wx1 * wy1;
    const bf16* k00 = Kpm + ((size_t)b * 1600 + x0 * 40 + y0) * 256 + hd * 64;
    const bf16* k01 = Kpm + ((size_t)b * 1600 + x0 * 40 + y1) * 256 + hd * 64;
    const bf16* k10 = Kpm + ((size_t)b * 1600 + x1 * 40 + y0) * 256 + hd * 64;
    const bf16* k11 = Kpm + ((size_t)b * 1600 + x1 * 40 + y1) * 256 + hd * 64;
    float dot = 0.f;
#pragma unroll
    for (int i = 0; i < 8; ++i) {
      bf16x8 qv = *(const bf16x8*)(Qs + pl * 136 + hl * 64 + i * 8);
      bf16x8 a = *(const bf16x8*)(k00 + i * 8);
      bf16x8 c = *(const bf16x8*)(k01 + i * 8);
      bf16x8 d = *(const bf16x8*)(k10 + i * 8);
      bf16x8 e = *(const bf16x8*)(k11 + i * 8);
#pragma unroll
      for (int j = 0; j < 8; ++j) {
        float kup = w00 * (float)a[j] + w01 * (float)c[j] + w10 * (float)d[j] + w11 * (float)e[j];
        dot += (float)qv[j] * kup;
      }
    }
    score[((size_t)b * 4 + hd) * 6400 + p] = dot * 0.0625f;
  }
}

// ---------------------------------------------------------------------------
// K+V projection: key f32 channel-major [B][256][1600] -> Kpm/Vpm bf16
// pixel-major [B][1600][256]. Same GEMM core; epilogue via padded LDS scratch
// for coalesced 16B stores. blockIdx.y: (y&1)=n-half, (y>>1)=K vs V.
// ---------------------------------------------------------------------------
__global__ __launch_bounds__(512, 1)
void kv_gemm(const float* __restrict__ key,
             const bf16* __restrict__ Wk, const float* __restrict__ bk, bf16* __restrict__ Kpm,
             const bf16* __restrict__ Wv, const float* __restrict__ bv, bf16* __restrict__ Vpm) {
  __shared__ alignas(16) char smem[65536];
  const int P = 1600;
  const int t = threadIdx.x;
  const int b = blockIdx.z;
  const int m0 = blockIdx.x * 128;
  const int sel = blockIdx.y >> 1;
  const int n0 = (blockIdx.y & 1) * 128;
  const bf16* W = sel ? Wv : Wk;
  const float* bias = sel ? bv : bk;
  bf16* out = sel ? Vpm : Kpm;
  const int w = t >> 6, l = t & 63;
  const int wr = w & 1, wc = w >> 1;
  const int lrow = l & 15, koff = (l >> 4) * 8;
  const int up = t & 31, uk = t >> 5;
  const float* actb = key + (size_t)b * 256 * P;

  f32x4 Ar[4];
  f32x4 acc[4][2];
#pragma unroll
  for (int i = 0; i < 4; ++i)
#pragma unroll
    for (int j = 0; j < 2; ++j) acc[i][j] = (f32x4){0.f, 0.f, 0.f, 0.f};

  auto Ab = [&](int buf) { return (bf16*)(smem + buf * 16384); };
  auto Bb = [&](int buf) { return (bf16*)(smem + 32768 + buf * 16384); };

  auto GLOADB = [&](int kt, int buf) {
    const int k0 = kt * 64;
#pragma unroll
    for (int call = 0; call < 2; ++call) {
      int idx = call * 512 + t;
      int row = idx >> 3, u = idx & 7;
      gl16(W + (size_t)(n0 + row) * 256 + k0 + ((u ^ (row & 7)) << 3), Bb(buf) + idx * 8);
    }
  };
  auto ALOAD = [&](int kt) {
    const int k0 = kt * 64;
    int ps = m0 + up * 4;
    if (ps > P - 4) ps = P - 4;  // tail: dup rows, masked at write-out
#pragma unroll
    for (int j = 0; j < 4; ++j)
      Ar[j] = *(const f32x4*)(actb + (size_t)(k0 + uk * 4 + j) * P + ps);
  };
  auto ASTORE = [&](int buf) {
#pragma unroll
    for (int j = 0; j < 4; ++j) {
      int row = up * 4 + j;
      int cs = (uk * 4) ^ ((row & 7) << 3);
      bf16x4 v = {(bf16)Ar[0][j], (bf16)Ar[1][j], (bf16)Ar[2][j], (bf16)Ar[3][j]};
      *(bf16x4*)(Ab(buf) + row * 64 + cs) = v;
    }
  };
  auto COMPUTE = [&](int buf) {
#pragma unroll
    for (int kk = 0; kk < 2; ++kk) {
      const int kb = kk * 32 + koff;
      bf16x8 af[4], bvv[2];
#pragma unroll
      for (int i = 0; i < 4; ++i) af[i] = frag(Ab(buf), wr * 64 + i * 16 + lrow, kb);
#pragma unroll
      for (int j = 0; j < 2; ++j) bvv[j] = frag(Bb(buf), wc * 32 + j * 16 + lrow, kb);
#pragma unroll
      for (int i = 0; i < 4; ++i)
#pragma unroll
        for (int j = 0; j < 2; ++j)
          acc[i][j] = __builtin_amdgcn_mfma_f32_16x16x32_bf16(af[i], bvv[j], acc[i][j], 0, 0, 0);
    }
  };

  GLOADB(0, 0);
  ALOAD(0);
  ASTORE(0);
  __syncthreads();
#pragma unroll
  for (int kt = 0; kt < 4; ++kt) {
    const int cur = kt & 1;
    if (kt < 3) { GLOADB(kt + 1, cur ^ 1); ALOAD(kt + 1); }
    __builtin_amdgcn_sched_barrier(0);
    COMPUTE(cur);
    if (kt < 3) ASTORE(cur ^ 1);
    __syncthreads();
  }

  // ---- acc -> LDS scratch [128 px][136 ch-stride], then coalesced write ----
  bf16* Sc = (bf16*)smem;
#pragma unroll
  for (int mi = 0; mi < 4; ++mi) {
#pragma unroll
    for (int ni = 0; ni < 2; ++ni) {
      int ch = wc * 32 + ni * 16 + (l & 15);
      float bvf = bias[n0 + ch];
#pragma unroll
      for (int r = 0; r < 4; ++r) {
        int p = wr * 64 + mi * 16 + (l >> 4) * 4 + r;
        Sc[p * 136 + ch] = (bf16)(acc[mi][ni][r] + bvf);
      }
    }
  }
  __syncthreads();
  bf16* ob = out + (size_t)b * P * 256;
#pragma unroll
  for (int pass = 0; pass < 4; ++pass) {
    int unit = pass * 512 + t;
    int row = unit >> 4, cu = unit & 15;
    if (m0 + row < P) {
      bf16x8 v = *(const bf16x8*)(Sc + row * 136 + cu * 8);
      *(bf16x8*)(ob + (size_t)(m0 + row) * 256 + n0 + cu * 8) = v;
    }
  }
}

// ---------------------------------------------------------------------------
// In-place column softmax over x (per b,hd,y), x4 (R2 sum) folded in.
// ---------------------------------------------------------------------------
__global__ void smax_kernel(float* __restrict__ score) {
  __shared__ float s[6400];
  const int hd = blockIdx.x, b = blockIdx.y, t = threadIdx.x;
  float* buf = score + ((size_t)b * 4 + hd) * 6400;
  for (int i = t; i < 6400; i += 256) s[i] = buf[i];
  __syncthreads();
  if (t < 80) {
    const int y = t;
    float m = -1e30f;
    for (int x = 0; x < 80; ++x) m = fmaxf(m, s[x * 80 + y]);
    float sum = 0.f;
    for (int x = 0; x < 80; ++x) {
      float e = __expf(s[x * 80 + y] - m);
      s[x * 80 + y] = e;
      sum += e;
    }
    float inv = 4.0f / sum;
    for (int x = 0; x < 80; ++x) buf[x * 80 + y] = s[x * 80 + y] * inv;
  }
}

// ---------------------------------------------------------------------------
// outpm[b][p][c] = attn[b][hd(c)][p] * bilinear(V)[c][p]   (bf16 pixel-major)
// ---------------------------------------------------------------------------
__global__ void outgen_kernel(const bf16* __restrict__ Vpm, const float* __restrict__ attn,
                              bf16* __restrict__ outpm) {
  __shared__ float Vx[40][256];
  __shared__ float at[4][80];
  const int x = blockIdx.x, b = blockIdx.y, t = threadIdx.x;

  float cx = 0.5f * x - 0.25f;
  int ix = (int)floorf(cx);
  float wx1 = cx - ix, wx0 = 1.f - wx1;
  int tx0 = ix < 0 ? 0 : ix, tx1 = (ix + 1 > 39) ? 39 : ix + 1;

  const bf16* r0 = Vpm + ((size_t)b * 1600 + tx0 * 40) * 256;
  const bf16* r1 = Vpm + ((size_t)b * 1600 + tx1 * 40) * 256;
  for (int ty = 0; ty < 40; ++ty)
    Vx[ty][t] = wx0 * (float)r0[ty * 256 + t] + wx1 * (float)r1[ty * 256 + t];
  for (int i = t; i < 320; i += 256) {
    int hd = i / 80, y = i % 80;
    at[hd][y] = attn[((size_t)b * 4 + hd) * 6400 + x * 80 + y];
  }
  __syncthreads();

  const int hd = t >> 6;
  bf16* ob = outpm + ((size_t)b * 6400 + x * 80) * 256;
  for (int y = 0; y < 80; ++y) {
    float cyv = 0.5f * y - 0.25f;
    int iy = (int)floorf(cyv);
    float wy1 = cyv - iy;
    int ty0 = iy < 0 ? 0 : iy, ty1 = (iy + 1 > 39) ? 39 : iy + 1;
    float v = (1.f - wy1) * Vx[ty0][t] + wy1 * Vx[ty1][t];
    ob[(size_t)y * 256 + t] = (bf16)(at[hd][y] * v);
  }
}

// ---------------------------------------------------------------------------
// Final conv: outpm bf16 pixel-major [B][6400][256] x Wo -> d_out f32
// channel-major [B][256][6400]. BOTH tiles via gload_lds (zero staging regs).
// ---------------------------------------------------------------------------
__global__ __launch_bounds__(512, 1)
void gemm_out(const bf16* __restrict__ act, const bf16* __restrict__ Wo,
              const float* __restrict__ bias, float* __restrict__ out) {
  __shared__ alignas(16) char smem[65536];
  const int t = threadIdx.x;
  const int b = blockIdx.z;
  const int m0 = blockIdx.x * 128;  // pixel base
  const int n0 = blockIdx.y * 128;  // out-channel base
  const int w = t >> 6, l = t & 63;
  const int wr = w & 1, wc = w >> 1;
  const int lrow = l & 15, koff = (l >> 4) * 8;
  const bf16* actb = act + (size_t)b * 6400 * 256;

  f32x4 acc[4][2];
#pragma unroll
  for (int i = 0; i < 4; ++i)
#pragma unroll
    for (int j = 0; j < 2; ++j) acc[i][j] = (f32x4){0.f, 0.f, 0.f, 0.f};

  auto Ab = [&](int buf) { return (bf16*)(smem + buf * 16384); };
  auto Bb = [&](int buf) { return (bf16*)(smem + 32768 + buf * 16384); };

  auto GLOADS = [&](int kt, int buf) {
    const int k0 = kt * 64;
#pragma unroll
    for (int call = 0; call < 2; ++call) {
      int idx = call * 512 + t;
      int row = idx >> 3, u = idx & 7;
      gl16(actb + (size_t)(m0 + row) * 256 + k0 + ((u ^ (row & 7)) << 3), Ab(buf) + idx * 8);
      gl16(Wo + (size_t)(n0 + row) * 256 + k0 + ((u ^ (row & 7)) << 3), Bb(buf) + idx * 8);
    }
  };
  auto COMPUTE = [&](int buf) {
#pragma unroll
    for (int kk = 0; kk < 2; ++kk) {
      const int kb = kk * 32 + koff;
      bf16x8 af[4], bvv[2];
#pragma unroll
      for (int i = 0; i < 4; ++i) af[i] = frag(Ab(buf), wr * 64 + i * 16 + lrow, kb);
#pragma unroll
      for (int j = 0; j < 2; ++j) bvv[j] = frag(Bb(buf), wc * 32 + j * 16 + lrow, kb);
#pragma unroll
      for (int i = 0; i < 4; ++i)
#pragma unroll
        for (int j = 0; j < 2; ++j)
          acc[i][j] = __builtin_amdgcn_mfma_f32_16x16x32_bf16(af[i], bvv[j], acc[i][j], 0, 0, 0);
    }
  };

  GLOADS(0, 0);
  __syncthreads();
#pragma unroll
  for (int kt = 0; kt < 4; ++kt) {
    const int cur = kt & 1;
    if (kt < 3) GLOADS(kt + 1, cur ^ 1);
    __builtin_amdgcn_sched_barrier(0);
    COMPUTE(cur);
    __syncthreads();
  }

  float* ob = out + (size_t)b * 256 * 6400;
#pragma unroll
  for (int mi = 0; mi < 4; ++mi) {
    int pbase = m0 + wr * 64 + mi * 16 + (l >> 4) * 4;
#pragma unroll
    for (int ni = 0; ni < 2; ++ni) {
      int o_ = n0 + wc * 32 + ni * 16 + (l & 15);
      float bvf = bias[o_];
      f32x4 v = {acc[mi][ni][0] + bvf, acc[mi][ni][1] + bvf,
                 acc[mi][ni][2] + bvf, acc[mi][ni][3] + bvf};
      *(f32x4*)(ob + (size_t)o_ * 6400 + pbase) = v;
    }
  }
}

// ---------------------------------------------------------------------------
extern "C" void kernel_launch(void* const* d_in, const int* in_sizes, int n_in,
                              void* d_out, int out_size, void* d_ws, size_t ws_size,
                              hipStream_t stream) {
  const float* query = (const float*)d_in[0];
  const float* key   = (const float*)d_in[1];
  const float* wq    = (const float*)d_in[2];
  const float* bq    = (const float*)d_in[3];
  const float* wk    = (const float*)d_in[4];
  const float* bk    = (const float*)d_in[5];
  const float* wv    = (const float*)d_in[6];
  const float* bv    = (const float*)d_in[7];
  const float* wo    = (const float*)d_in[8];
  const float* bo    = (const float*)d_in[9];

  // ws layout (85.7 MB): outpm | Kpm | Vpm | score | Wb[4]
  char* ws = (char*)d_ws;
  bf16*  outpm = (bf16*)(ws);              // 52,428,800 B
  bf16*  Kpm   = (bf16*)(ws + 52428800);   // 13,107,200 B
  bf16*  Vpm   = (bf16*)(ws + 65536000);   // 13,107,200 B
  float* score = (float*)(ws + 78643200);  //  6,553,600 B
  bf16*  Wb    = (bf16*)(ws + 85196800);   //    524,288 B: wq,wk,wv,wo bf16
  bf16* wqb = Wb, *wkb = Wb + 65536, *wvb = Wb + 131072, *wob = Wb + 196608;

  wpre<<<dim3(32, 4), 256, 0, stream>>>(wq, wk, wv, wo, Wb);
  kv_gemm<<<dim3(13, 4, 16), 512, 0, stream>>>(key, wkb, bk, Kpm, wvb, bv, Vpm);
  qgemm_score<<<dim3(50, 2, 16), 512, 0, stream>>>(query, wqb, bq, Kpm, score);
  smax_kernel<<<dim3(4, 16), 256, 0, stream>>>(score);
  outgen_kernel<<<dim3(80, 16), 256, 0, stream>>>(Vpm, score, outpm);
  gemm_out<<<dim3(50, 2, 16), 512, 0, stream>>>(outpm, wob, bo, (float*)d_out);
}

// Round 8
// 172.890 us; speedup vs baseline: 1.2060x; 1.0389x over previous
//
#include <hip/hip_runtime.h>
#include <hip/hip_bf16.h>

typedef __bf16 bf16;
typedef __attribute__((ext_vector_type(4))) float f32x4;
typedef __attribute__((ext_vector_type(8))) __bf16 bf16x8;
typedef __attribute__((ext_vector_type(4))) __bf16 bf16x4;

// async global->LDS, 16B per lane; LDS dest must be wave-uniform base + lane*16
static __device__ __forceinline__ void gl16(const void* g, void* l) {
  __builtin_amdgcn_global_load_lds((const __attribute__((address_space(1))) void*)g,
                                   (__attribute__((address_space(3))) void*)l, 16, 0, 0);
}
// fragment read from a [*][64] bf16 tile, 16B-unit XOR swizzle by (row&7)
static __device__ __forceinline__ bf16x8 frag(const bf16* tile, int row, int kb) {
  return *(const bf16x8*)(tile + row * 64 + ((((kb) >> 3) ^ (row & 7)) << 3));
}

// ---------------------------------------------------------------------------
// Weight prepass: 4x [256][256] f32 -> bf16 row-major.
// ---------------------------------------------------------------------------
__global__ void wpre(const float* __restrict__ w0, const float* __restrict__ w1,
                     const float* __restrict__ w2, const float* __restrict__ w3,
                     bf16* __restrict__ dst) {
  const float* srcs[4] = {w0, w1, w2, w3};
  const float* s = srcs[blockIdx.y];
  bf16* d = dst + (size_t)blockIdx.y * 65536;
  int base = blockIdx.x * 2048 + threadIdx.x * 8;
  f32x4 a = *(const f32x4*)(s + base);
  f32x4 b = *(const f32x4*)(s + base + 4);
  bf16x8 v = {(bf16)a[0], (bf16)a[1], (bf16)a[2], (bf16)a[3],
              (bf16)b[0], (bf16)b[1], (bf16)b[2], (bf16)b[3]};
  *(bf16x8*)(d + base) = v;
}

// ===========================================================================
// Fused Q-projection + score, restructured for occupancy.
// Block: 64 px x 256 out-ch, 256 threads (4 waves; wave w owns o = w*64..+63).
// act tile [64 px][64 c] bf16 in LDS (transposed in staging, XOR-swizzled),
// double-buffered (2x8KB). W-fragments read per-kt straight from L2-resident
// global bf16 (no staging). 32 MFMA/wave/kt. Epilogue: Q -> LDS -> score.
// ===========================================================================
__global__ __launch_bounds__(256, 3)
void qscore(const float* __restrict__ query, const bf16* __restrict__ Wq,
            const float* __restrict__ bq, const bf16* __restrict__ Kpm,
            float* __restrict__ score) {
  __shared__ alignas(16) char smem[64 * 264 * 2];  // 33.8KB: act dbuf (16KB) / Qs
  const int t = threadIdx.x;
  const int b = blockIdx.z;
  const int p0 = blockIdx.x * 64;
  const int w = t >> 6, l = t & 63;
  const int lrow = l & 15, ksel = l >> 4;        // fragment lane decomposition
  const int pq = t & 15, cq = t >> 4;            // staging: px-quad, c-quad
  const float* actb = query + (size_t)b * 256 * 6400;

  auto Bt = [&](int buf) { return (bf16*)(smem + buf * 8192); };

  f32x4 Ar[4];  // staging regs: rows c = k0+cq*4+j, px pq*4..pq*4+3
  auto ALOAD = [&](int kt) {
    const int k0 = kt * 64;
#pragma unroll
    for (int j = 0; j < 4; ++j)
      Ar[j] = *(const f32x4*)(actb + (size_t)(k0 + cq * 4 + j) * 6400 + p0 + pq * 4);
  };
  auto ASTORE = [&](int buf) {
    bf16* tile = Bt(buf);
#pragma unroll
    for (int e = 0; e < 4; ++e) {   // 4x4 in-register transpose
      int row = pq * 4 + e;         // px
      bf16x4 v = {(bf16)Ar[0][e], (bf16)Ar[1][e], (bf16)Ar[2][e], (bf16)Ar[3][e]};
      // elem addr: row*64 + swizzled unit; unit=(cq>>1)^(row&7), half=(cq&1)
      *(bf16x4*)(tile + row * 64 + ((((cq >> 1) ^ (row & 7)) << 3) | ((cq & 1) << 2))) = v;
    }
  };

  f32x4 acc[4][4];
#pragma unroll
  for (int i = 0; i < 4; ++i)
#pragma unroll
    for (int j = 0; j < 4; ++j) acc[i][j] = (f32x4){0.f, 0.f, 0.f, 0.f};

  auto COMPUTE = [&](int kt, int buf) {
    const int k0 = kt * 64;
    // W fragments from global (L2-resident, 128KB total): 8 x 16B per wave
    bf16x8 af[4][2];
#pragma unroll
    for (int mi = 0; mi < 4; ++mi)
#pragma unroll
      for (int kk = 0; kk < 2; ++kk)
        af[mi][kk] = *(const bf16x8*)(Wq + (size_t)(w * 64 + mi * 16 + lrow) * 256 +
                                      k0 + kk * 32 + ksel * 8);
    bf16x8 bv[4][2];
#pragma unroll
    for (int ni = 0; ni < 4; ++ni)
#pragma unroll
      for (int kk = 0; kk < 2; ++kk)
        bv[ni][kk] = frag(Bt(buf), ni * 16 + lrow, kk * 32 + ksel * 8);
#pragma unroll
    for (int kk = 0; kk < 2; ++kk)
#pragma unroll
      for (int mi = 0; mi < 4; ++mi)
#pragma unroll
        for (int ni = 0; ni < 4; ++ni)
          acc[mi][ni] = __builtin_amdgcn_mfma_f32_16x16x32_bf16(af[mi][kk], bv[ni][kk],
                                                                acc[mi][ni], 0, 0, 0);
  };

  ALOAD(0);
  ASTORE(0);
  __syncthreads();
#pragma unroll
  for (int kt = 0; kt < 4; ++kt) {
    if (kt < 3) ALOAD(kt + 1);      // prefetch next act chunk (regs)
    COMPUTE(kt, kt & 1);
    if (kt < 3) ASTORE((kt + 1) & 1);
    __syncthreads();
  }

  // ---- dump Q (with bias) to LDS Qs[64 px][264 ch-stride] ----
  __syncthreads();                   // retire last COMPUTE's reads before overwrite
  bf16* Qs = (bf16*)smem;
#pragma unroll
  for (int mi = 0; mi < 4; ++mi) {
#pragma unroll
    for (int r = 0; r < 4; ++r) {
      int o = w * 64 + mi * 16 + ksel * 4 + r;
      float bvf = bq[o];
#pragma unroll
      for (int ni = 0; ni < 4; ++ni) {
        int px = ni * 16 + lrow;
        Qs[px * 264 + o] = (bf16)(acc[mi][ni][r] + bvf);
      }
    }
  }
  __syncthreads();

  // ---- score: one thread per (pixel, head); K from L3-resident Kpm ----
  {
    int pl = t & 63, hd = t >> 6;
    int p = p0 + pl;
    int x = p / 80, y = p % 80;
    float cx = 0.5f * x - 0.25f;
    int ix = (int)floorf(cx);
    float wx1 = cx - ix;
    int x0 = ix < 0 ? 0 : ix, x1 = (ix + 1 > 39) ? 39 : ix + 1;
    float cy = 0.5f * y - 0.25f;
    int iy = (int)floorf(cy);
    float wy1 = cy - iy;
    int y0 = iy < 0 ? 0 : iy, y1 = (iy + 1 > 39) ? 39 : iy + 1;
    float w00 = (1.f - wx1) * (1.f - wy1), w01 = (1.f - wx1) * wy1;
    float w10 = wx1 * (1.f - wy1), w11 = wx1 * wy1;
    const bf16* k00 = Kpm + ((size_t)b * 1600 + x0 * 40 + y0) * 256 + hd * 64;
    const bf16* k01 = Kpm + ((size_t)b * 1600 + x0 * 40 + y1) * 256 + hd * 64;
    const bf16* k10 = Kpm + ((size_t)b * 1600 + x1 * 40 + y0) * 256 + hd * 64;
    const bf16* k11 = Kpm + ((size_t)b * 1600 + x1 * 40 + y1) * 256 + hd * 64;
    float dot = 0.f;
#pragma unroll
    for (int i = 0; i < 8; ++i) {
      bf16x8 qv = *(const bf16x8*)(Qs + pl * 264 + hd * 64 + i * 8);
      bf16x8 a = *(const bf16x8*)(k00 + i * 8);
      bf16x8 c = *(const bf16x8*)(k01 + i * 8);
      bf16x8 d = *(const bf16x8*)(k10 + i * 8);
      bf16x8 e = *(const bf16x8*)(k11 + i * 8);
#pragma unroll
      for (int j = 0; j < 8; ++j) {
        float kup = w00 * (float)a[j] + w01 * (float)c[j] + w10 * (float)d[j] + w11 * (float)e[j];
        dot += (float)qv[j] * kup;
      }
    }
    score[((size_t)b * 4 + hd) * 6400 + p] = dot * 0.0625f;
  }
}

// ---------------------------------------------------------------------------
// K+V projection (unchanged from round 7).
// ---------------------------------------------------------------------------
__global__ __launch_bounds__(512, 1)
void kv_gemm(const float* __restrict__ key,
             const bf16* __restrict__ Wk, const float* __restrict__ bk, bf16* __restrict__ Kpm,
             const bf16* __restrict__ Wv, const float* __restrict__ bv, bf16* __restrict__ Vpm) {
  __shared__ alignas(16) char smem[65536];
  const int P = 1600;
  const int t = threadIdx.x;
  const int b = blockIdx.z;
  const int m0 = blockIdx.x * 128;
  const int sel = blockIdx.y >> 1;
  const int n0 = (blockIdx.y & 1) * 128;
  const bf16* W = sel ? Wv : Wk;
  const float* bias = sel ? bv : bk;
  bf16* out = sel ? Vpm : Kpm;
  const int w = t >> 6, l = t & 63;
  const int wr = w & 1, wc = w >> 1;
  const int lrow = l & 15, koff = (l >> 4) * 8;
  const int up = t & 31, uk = t >> 5;
  const float* actb = key + (size_t)b * 256 * P;

  f32x4 Ar[4];
  f32x4 acc[4][2];
#pragma unroll
  for (int i = 0; i < 4; ++i)
#pragma unroll
    for (int j = 0; j < 2; ++j) acc[i][j] = (f32x4){0.f, 0.f, 0.f, 0.f};

  auto Ab = [&](int buf) { return (bf16*)(smem + buf * 16384); };
  auto Bb = [&](int buf) { return (bf16*)(smem + 32768 + buf * 16384); };

  auto GLOADB = [&](int kt, int buf) {
    const int k0 = kt * 64;
#pragma unroll
    for (int call = 0; call < 2; ++call) {
      int idx = call * 512 + t;
      int row = idx >> 3, u = idx & 7;
      gl16(W + (size_t)(n0 + row) * 256 + k0 + ((u ^ (row & 7)) << 3), Bb(buf) + idx * 8);
    }
  };
  auto ALOAD = [&](int kt) {
    const int k0 = kt * 64;
    int ps = m0 + up * 4;
    if (ps > P - 4) ps = P - 4;
#pragma unroll
    for (int j = 0; j < 4; ++j)
      Ar[j] = *(const f32x4*)(actb + (size_t)(k0 + uk * 4 + j) * P + ps);
  };
  auto ASTORE = [&](int buf) {
#pragma unroll
    for (int j = 0; j < 4; ++j) {
      int row = up * 4 + j;
      int cs = (uk * 4) ^ ((row & 7) << 3);
      bf16x4 v = {(bf16)Ar[0][j], (bf16)Ar[1][j], (bf16)Ar[2][j], (bf16)Ar[3][j]};
      *(bf16x4*)(Ab(buf) + row * 64 + cs) = v;
    }
  };
  auto COMPUTE = [&](int buf) {
#pragma unroll
    for (int kk = 0; kk < 2; ++kk) {
      bf16x8 af[4], bvv[2];
      const int kb = kk * 32 + koff;
#pragma unroll
      for (int i = 0; i < 4; ++i) af[i] = frag(Ab(buf), wr * 64 + i * 16 + lrow, kb);
#pragma unroll
      for (int j = 0; j < 2; ++j) bvv[j] = frag(Bb(buf), wc * 32 + j * 16 + lrow, kb);
#pragma unroll
      for (int i = 0; i < 4; ++i)
#pragma unroll
        for (int j = 0; j < 2; ++j)
          acc[i][j] = __builtin_amdgcn_mfma_f32_16x16x32_bf16(af[i], bvv[j], acc[i][j], 0, 0, 0);
    }
  };

  GLOADB(0, 0);
  ALOAD(0);
  ASTORE(0);
  __syncthreads();
#pragma unroll
  for (int kt = 0; kt < 4; ++kt) {
    const int cur = kt & 1;
    if (kt < 3) { GLOADB(kt + 1, cur ^ 1); ALOAD(kt + 1); }
    __builtin_amdgcn_sched_barrier(0);
    COMPUTE(cur);
    if (kt < 3) ASTORE(cur ^ 1);
    __syncthreads();
  }

  bf16* Sc = (bf16*)smem;
#pragma unroll
  for (int mi = 0; mi < 4; ++mi) {
#pragma unroll
    for (int ni = 0; ni < 2; ++ni) {
      int ch = wc * 32 + ni * 16 + (l & 15);
      float bvf = bias[n0 + ch];
#pragma unroll
      for (int r = 0; r < 4; ++r) {
        int p = wr * 64 + mi * 16 + (l >> 4) * 4 + r;
        Sc[p * 136 + ch] = (bf16)(acc[mi][ni][r] + bvf);
      }
    }
  }
  __syncthreads();
  bf16* ob = out + (size_t)b * P * 256;
#pragma unroll
  for (int pass = 0; pass < 4; ++pass) {
    int unit = pass * 512 + t;
    int row = unit >> 4, cu = unit & 15;
    if (m0 + row < P) {
      bf16x8 v = *(const bf16x8*)(Sc + row * 136 + cu * 8);
      *(bf16x8*)(ob + (size_t)(m0 + row) * 256 + n0 + cu * 8) = v;
    }
  }
}

// ---------------------------------------------------------------------------
// In-place column softmax over x (per b,hd,y), x4 (R2 sum) folded in.
// ---------------------------------------------------------------------------
__global__ void smax_kernel(float* __restrict__ score) {
  __shared__ float s[6400];
  const int hd = blockIdx.x, b = blockIdx.y, t = threadIdx.x;
  float* buf = score + ((size_t)b * 4 + hd) * 6400;
  for (int i = t; i < 6400; i += 256) s[i] = buf[i];
  __syncthreads();
  if (t < 80) {
    const int y = t;
    float m = -1e30f;
    for (int x = 0; x < 80; ++x) m = fmaxf(m, s[x * 80 + y]);
    float sum = 0.f;
    for (int x = 0; x < 80; ++x) {
      float e = __expf(s[x * 80 + y] - m);
      s[x * 80 + y] = e;
      sum += e;
    }
    float inv = 4.0f / sum;
    for (int x = 0; x < 80; ++x) buf[x * 80 + y] = s[x * 80 + y] * inv;
  }
}

// ---------------------------------------------------------------------------
// outpm[b][p][c] = attn[b][hd(c)][p] * bilinear(V)[c][p]   (bf16 pixel-major)
// ---------------------------------------------------------------------------
__global__ void outgen_kernel(const bf16* __restrict__ Vpm, const float* __restrict__ attn,
                              bf16* __restrict__ outpm) {
  __shared__ float Vx[40][256];
  __shared__ float at[4][80];
  const int x = blockIdx.x, b = blockIdx.y, t = threadIdx.x;

  float cx = 0.5f * x - 0.25f;
  int ix = (int)floorf(cx);
  float wx1 = cx - ix, wx0 = 1.f - wx1;
  int tx0 = ix < 0 ? 0 : ix, tx1 = (ix + 1 > 39) ? 39 : ix + 1;

  const bf16* r0 = Vpm + ((size_t)b * 1600 + tx0 * 40) * 256;
  const bf16* r1 = Vpm + ((size_t)b * 1600 + tx1 * 40) * 256;
  for (int ty = 0; ty < 40; ++ty)
    Vx[ty][t] = wx0 * (float)r0[ty * 256 + t] + wx1 * (float)r1[ty * 256 + t];
  for (int i = t; i < 320; i += 256) {
    int hd = i / 80, y = i % 80;
    at[hd][y] = attn[((size_t)b * 4 + hd) * 6400 + x * 80 + y];
  }
  __syncthreads();

  const int hd = t >> 6;
  bf16* ob = outpm + ((size_t)b * 6400 + x * 80) * 256;
  for (int y = 0; y < 80; ++y) {
    float cyv = 0.5f * y - 0.25f;
    int iy = (int)floorf(cyv);
    float wy1 = cyv - iy;
    int ty0 = iy < 0 ? 0 : iy, ty1 = (iy + 1 > 39) ? 39 : iy + 1;
    float v = (1.f - wy1) * Vx[ty0][t] + wy1 * Vx[ty1][t];
    ob[(size_t)y * 256 + t] = (bf16)(at[hd][y] * v);
  }
}

// ---------------------------------------------------------------------------
// Final conv (unchanged from round 7): both tiles via gload_lds.
// ---------------------------------------------------------------------------
__global__ __launch_bounds__(512, 1)
void gemm_out(const bf16* __restrict__ act, const bf16* __restrict__ Wo,
              const float* __restrict__ bias, float* __restrict__ out) {
  __shared__ alignas(16) char smem[65536];
  const int t = threadIdx.x;
  const int b = blockIdx.z;
  const int m0 = blockIdx.x * 128;
  const int n0 = blockIdx.y * 128;
  const int w = t >> 6, l = t & 63;
  const int wr = w & 1, wc = w >> 1;
  const int lrow = l & 15, koff = (l >> 4) * 8;
  const bf16* actb = act + (size_t)b * 6400 * 256;

  f32x4 acc[4][2];
#pragma unroll
  for (int i = 0; i < 4; ++i)
#pragma unroll
    for (int j = 0; j < 2; ++j) acc[i][j] = (f32x4){0.f, 0.f, 0.f, 0.f};

  auto Ab = [&](int buf) { return (bf16*)(smem + buf * 16384); };
  auto Bb = [&](int buf) { return (bf16*)(smem + 32768 + buf * 16384); };

  auto GLOADS = [&](int kt, int buf) {
    const int k0 = kt * 64;
#pragma unroll
    for (int call = 0; call < 2; ++call) {
      int idx = call * 512 + t;
      int row = idx >> 3, u = idx & 7;
      gl16(actb + (size_t)(m0 + row) * 256 + k0 + ((u ^ (row & 7)) << 3), Ab(buf) + idx * 8);
      gl16(Wo + (size_t)(n0 + row) * 256 + k0 + ((u ^ (row & 7)) << 3), Bb(buf) + idx * 8);
    }
  };
  auto COMPUTE = [&](int buf) {
#pragma unroll
    for (int kk = 0; kk < 2; ++kk) {
      bf16x8 af[4], bvv[2];
      const int kb = kk * 32 + koff;
#pragma unroll
      for (int i = 0; i < 4; ++i) af[i] = frag(Ab(buf), wr * 64 + i * 16 + lrow, kb);
#pragma unroll
      for (int j = 0; j < 2; ++j) bvv[j] = frag(Bb(buf), wc * 32 + j * 16 + lrow, kb);
#pragma unroll
      for (int i = 0; i < 4; ++i)
#pragma unroll
        for (int j = 0; j < 2; ++j)
          acc[i][j] = __builtin_amdgcn_mfma_f32_16x16x32_bf16(af[i], bvv[j], acc[i][j], 0, 0, 0);
    }
  };

  GLOADS(0, 0);
  __syncthreads();
#pragma unroll
  for (int kt = 0; kt < 4; ++kt) {
    const int cur = kt & 1;
    if (kt < 3) GLOADS(kt + 1, cur ^ 1);
    __builtin_amdgcn_sched_barrier(0);
    COMPUTE(cur);
    __syncthreads();
  }

  float* ob = out + (size_t)b * 256 * 6400;
#pragma unroll
  for (int mi = 0; mi < 4; ++mi) {
    int pbase = m0 + wr * 64 + mi * 16 + (l >> 4) * 4;
#pragma unroll
    for (int ni = 0; ni < 2; ++ni) {
      int o_ = n0 + wc * 32 + ni * 16 + (l & 15);
      float bvf = bias[o_];
      f32x4 v = {acc[mi][ni][0] + bvf, acc[mi][ni][1] + bvf,
                 acc[mi][ni][2] + bvf, acc[mi][ni][3] + bvf};
      *(f32x4*)(ob + (size_t)o_ * 6400 + pbase) = v;
    }
  }
}

// ---------------------------------------------------------------------------
extern "C" void kernel_launch(void* const* d_in, const int* in_sizes, int n_in,
                              void* d_out, int out_size, void* d_ws, size_t ws_size,
                              hipStream_t stream) {
  const float* query = (const float*)d_in[0];
  const float* key   = (const float*)d_in[1];
  const float* wq    = (const float*)d_in[2];
  const float* bq    = (const float*)d_in[3];
  const float* wk    = (const float*)d_in[4];
  const float* bk    = (const float*)d_in[5];
  const float* wv    = (const float*)d_in[6];
  const float* bv    = (const float*)d_in[7];
  const float* wo    = (const float*)d_in[8];
  const float* bo    = (const float*)d_in[9];

  // ws layout (85.7 MB): outpm | Kpm | Vpm | score | Wb[4]
  char* ws = (char*)d_ws;
  bf16*  outpm = (bf16*)(ws);              // 52,428,800 B
  bf16*  Kpm   = (bf16*)(ws + 52428800);   // 13,107,200 B
  bf16*  Vpm   = (bf16*)(ws + 65536000);   // 13,107,200 B
  float* score = (float*)(ws + 78643200);  //  6,553,600 B
  bf16*  Wb    = (bf16*)(ws + 85196800);   //    524,288 B: wq,wk,wv,wo bf16
  bf16* wqb = Wb, *wkb = Wb + 65536, *wvb = Wb + 131072, *wob = Wb + 196608;

  wpre<<<dim3(32, 4), 256, 0, stream>>>(wq, wk, wv, wo, Wb);
  kv_gemm<<<dim3(13, 4, 16), 512, 0, stream>>>(key, wkb, bk, Kpm, wvb, bv, Vpm);
  qscore<<<dim3(100, 1, 16), 256, 0, stream>>>(query, wqb, bq, Kpm, score);
  smax_kernel<<<dim3(4, 16), 256, 0, stream>>>(score);
  outgen_kernel<<<dim3(80, 16), 256, 0, stream>>>(Vpm, score, outpm);
  gemm_out<<<dim3(50, 2, 16), 512, 0, stream>>>(outpm, wob, bo, (float*)d_out);
}